// Round 1
// 1263.308 us; speedup vs baseline: 1.1931x; 1.1931x over previous
//
#include <hip/hip_runtime.h>
#include <math.h>

#define N_EMBD 768
#define N_EXP  8
#define DIMH   2048
#define CAPN   1024
#define M_TOT  8192

typedef __bf16 bf16x8 __attribute__((ext_vector_type(8)));
typedef float  f32x4  __attribute__((ext_vector_type(4)));

__device__ __forceinline__ unsigned short f2bf(float f) {
    unsigned int u = __float_as_uint(f);
    unsigned int r = (u + 0x7fffu + ((u >> 16) & 1u)) >> 16;
    return (unsigned short)r;
}

__device__ __forceinline__ void gload16(const void* g, void* l) {
    __builtin_amdgcn_global_load_lds(
        (const __attribute__((address_space(1))) unsigned int*)g,
        (__attribute__((address_space(3))) unsigned int*)l, 16, 0, 0);
}

// ---------------------------------------------------------------------------
// Kernel A: per-row L2 norm + scale + gamma + fp32->bf16.  One block per row.
// ---------------------------------------------------------------------------
__global__ __launch_bounds__(256) void norm_convert_kernel(
        const float* __restrict__ x, const float* __restrict__ gamma,
        unsigned short* __restrict__ h) {
    int r = blockIdx.x;                 // 0..65535
    int e = r >> 13, m = r & 8191;
    int b = m >> 10, nc = m & 1023;
    const float* row = x + (size_t)((b * N_EXP + e) * CAPN + nc) * N_EMBD;
    unsigned short* orow = h + (size_t)(e * M_TOT + m) * N_EMBD;
    int t = threadIdx.x;

    float v0 = row[t], v1 = row[t + 256], v2 = row[t + 512];
    float acc = v0 * v0 + v1 * v1 + v2 * v2;
#pragma unroll
    for (int off = 32; off >= 1; off >>= 1) acc += __shfl_down(acc, off, 64);
    __shared__ float part[4];
    if ((t & 63) == 0) part[t >> 6] = acc;
    __syncthreads();
    float tot = part[0] + part[1] + part[2] + part[3];
    float s = 27.712812921102035f / fmaxf(sqrtf(tot), 1e-12f);

    orow[t]       = f2bf(v0 * s * gamma[t]);
    orow[t + 256] = f2bf(v1 * s * gamma[t + 256]);
    orow[t + 512] = f2bf(v2 * s * gamma[t + 512]);
}

// ---------------------------------------------------------------------------
// Kernel B: transpose + convert weights. in: [z][R][C] fp32 -> out: [z][C][R] bf16
// ---------------------------------------------------------------------------
__global__ __launch_bounds__(256) void transpose_convert_kernel(
        const float* __restrict__ in, unsigned short* __restrict__ out, int R, int C) {
    __shared__ float tile[32][33];
    int c0 = blockIdx.x * 32, r0 = blockIdx.y * 32;
    const float* ip = in + (size_t)blockIdx.z * R * C;
    unsigned short* op = out + (size_t)blockIdx.z * R * C;
    int tx = threadIdx.x & 31, ty = threadIdx.x >> 5;
#pragma unroll
    for (int i = 0; i < 4; ++i)
        tile[ty + 8 * i][tx] = ip[(size_t)(r0 + ty + 8 * i) * C + c0 + tx];
    __syncthreads();
#pragma unroll
    for (int i = 0; i < 4; ++i)
        op[(size_t)(c0 + ty + 8 * i) * R + r0 + tx] = f2bf(tile[tx][ty + 8 * i]);
}

// ---------------------------------------------------------------------------
// 8-phase 256-row GEMM machinery (T2 swizzle + T3/T4 counted vmcnt + T5 prio)
// LDS per dbuf: 32768 shorts (64KB); dbuf stride 32768; total 128KB.
// XOR swizzle: LDS[row][slot] holds global[row][slot ^ (row&7)] (slot = 16B unit).
// ---------------------------------------------------------------------------
#define SBB  __builtin_amdgcn_s_barrier(); \
             asm volatile("s_waitcnt lgkmcnt(0)" ::: "memory"); \
             __builtin_amdgcn_sched_barrier(0); \
             __builtin_amdgcn_s_setprio(1)
#define SBE  __builtin_amdgcn_s_setprio(0); __builtin_amdgcn_s_barrier()
#define VMW(N) do { asm volatile("s_waitcnt vmcnt(" #N ")" ::: "memory"); \
             __builtin_amdgcn_sched_barrier(0); } while (0)

// stage one 128x64 half-tile: 512 thr x 2 loads x 16B; linear LDS dest,
// inverse-swizzled global source (rule #21).
#define STG2(PSRC, RS, KT, DOFF) do { \
    gload16((PSRC) + (size_t)sr * (RS) + (size_t)(KT) * 64 + scs, lds + (DOFF) + ldst); \
    gload16((PSRC) + (size_t)(sr + 64) * (RS) + (size_t)(KT) * 64 + scs, lds + (DOFF) + ldst + 4096); \
  } while (0)

#define RDF(V) (*(const bf16x8*)(lds + (V)))

#define RDA4(AF, DB, IB) do { \
    _Pragma("unroll") for (int i_ = 0; i_ < 4; ++i_) { \
      AF[i_][0] = RDF((DB)*32768 + aB + ((IB) + i_)*1024 + sl0); \
      AF[i_][1] = RDF((DB)*32768 + aB + ((IB) + i_)*1024 + sl1); } \
  } while (0)

#define RDB2(BF, DB, BASE) do { \
    _Pragma("unroll") for (int j_ = 0; j_ < 2; ++j_) { \
      BF[j_][0] = RDF((DB)*32768 + (BASE) + j_*1024 + sl0); \
      BF[j_][1] = RDF((DB)*32768 + (BASE) + j_*1024 + sl1); } \
  } while (0)

#define QUAD(ACC, MS, NB, AF, BF) do { \
    _Pragma("unroll") for (int i_ = 0; i_ < 4; ++i_) \
    _Pragma("unroll") for (int j_ = 0; j_ < 2; ++j_) { \
      ACC[(MS)*4 + i_][(NB) + j_] = __builtin_amdgcn_mfma_f32_16x16x32_bf16( \
          AF[i_][0], BF[j_][0], ACC[(MS)*4 + i_][(NB) + j_], 0, 0, 0); \
      ACC[(MS)*4 + i_][(NB) + j_] = __builtin_amdgcn_mfma_f32_16x16x32_bf16( \
          AF[i_][1], BF[j_][1], ACC[(MS)*4 + i_][(NB) + j_], 0, 0, 0); } \
  } while (0)

// ---------------------------------------------------------------------------
// Kernel C: GEMM1 + GLU epilogue. Block tile: 256(M) x 128(g-cols), BK=64.
// Computes u_v (256x128) and u_g (256x128) simultaneously; g = gelu(u_g)*u_v*mb.
// 512 thr = 8 waves (2M x 4N); per-wave 128x32 of v AND gate; 64 MFMA/K-tile/wave.
// ---------------------------------------------------------------------------
__global__ __launch_bounds__(512, 2) void gemm1_kernel(
        const unsigned short* __restrict__ hb,   // [E][8192][768]
        const unsigned short* __restrict__ fT,   // [E][4096][768] (rows 0..2047 = v, 2048.. = gate)
        const float* __restrict__ mbias,         // [2048]
        unsigned short* __restrict__ gb,         // [z][8192][2048]
        int e0) {
    __shared__ __align__(16) unsigned short lds[65536];   // 128 KiB
    const int t = threadIdx.x;
    const int e = e0 + blockIdx.z;
    const int m0 = blockIdx.x * 256;
    const int n0 = blockIdx.y * 128;
    const unsigned short* pA  = hb + ((size_t)e * M_TOT + m0) * N_EMBD;
    const unsigned short* pBv = fT + ((size_t)e * 2 * DIMH + n0) * N_EMBD;
    const unsigned short* pBg = pBv + (size_t)DIMH * N_EMBD;
    unsigned short* pG = gb + (size_t)blockIdx.z * M_TOT * DIMH;

    // staging thread mapping (rows sr, sr+64 of a 128-row half; xor-swz source col)
    const int sr   = t >> 3;
    const int scs  = ((t & 7) ^ (sr & 7)) * 8;
    const int ldst = t * 8;
    // fragment mapping
    const int lane = t & 63, lo = lane & 15, quad = lane >> 4;
    const int w = t >> 6, wm = w & 1, wn = w >> 1;
    const int sl0 = ((quad    ) ^ (lo & 7)) * 8;
    const int sl1 = ((quad + 4) ^ (lo & 7)) * 8;
    const int aB  = wm * 8192 + lo * 64;                 // A half wm, row lo (+i*1024)
    const int bvB = 16384 + (wn * 32 + lo) * 64;         // Bv rows (+j*1024)
    const int bgB = 24576 + (wn * 32 + lo) * 64;         // Bg rows

#define STA1(D, H, KT)  STG2(pA + (size_t)(H) * 128 * N_EMBD, N_EMBD, KT, (D)*32768 + (H)*8192)
#define STBV1(D, KT)    STG2(pBv, N_EMBD, KT, (D)*32768 + 16384)
#define STBG1(D, KT)    STG2(pBg, N_EMBD, KT, (D)*32768 + 24576)

    f32x4 accv[8][2], accg[8][2];
#pragma unroll
    for (int i = 0; i < 8; ++i)
#pragma unroll
        for (int j = 0; j < 2; ++j) { accv[i][j] = (f32x4)0.f; accg[i][j] = (f32x4)0.f; }
    bf16x8 a0[4][2], a1[4][2], bv[2][2], bg[2][2];

    // prologue: T0 full (dbuf0) + T1.Ah0 (dbuf1); keep T1.Ah0 in flight
    STA1(0, 0, 0); STA1(0, 1, 0); STBV1(0, 0); STBG1(0, 0); STA1(1, 0, 1);
    VMW(2);
    __builtin_amdgcn_s_barrier();

    for (int it = 0; it < 6; ++it) {                     // 12 K-tiles, 2 per iter
        const int kb = 2 * it + 1, kc = kb + 1, kd = kb + 2;
        const bool more = (it < 5);
        // P1: read T_even A0-3 + Bv; finish staging T_odd.Ah1
        RDA4(a0, 0, 0); RDB2(bv, 0, bvB);
        STA1(1, 1, kb);
        SBB; QUAD(accv, 0, 0, a0, bv); SBE;
        // P2: read A4-7; stage T_odd.Bv
        RDA4(a1, 0, 4);
        STBV1(1, kb);
        SBB; QUAD(accv, 1, 0, a1, bv); SBE;
        // P3: read Bg; stage T_odd.Bg
        RDB2(bg, 0, bgB);
        STBG1(1, kb);
        SBB; QUAD(accg, 1, 0, a1, bg); SBE;
        // P4: stage T_next_even.Ah0; counted gate for T_odd
        if (more) { STA1(0, 0, kc); VMW(2); } else { VMW(0); }
        SBB; QUAD(accg, 0, 0, a0, bg); SBE;
        // P5: read T_odd A0-3 + Bv; stage next_even.Ah1
        RDA4(a0, 1, 0); RDB2(bv, 1, bvB);
        if (more) STA1(0, 1, kc);
        SBB; QUAD(accv, 0, 0, a0, bv); SBE;
        // P6
        RDA4(a1, 1, 4);
        if (more) STBV1(0, kc);
        SBB; QUAD(accv, 1, 0, a1, bv); SBE;
        // P7
        RDB2(bg, 1, bgB);
        if (more) STBG1(0, kc);
        SBB; QUAD(accg, 1, 0, a1, bg); SBE;
        // P8: stage next_odd.Ah0; counted gate for next_even
        if (more) { STA1(1, 0, kd); VMW(2); } else { VMW(0); }
        SBB; QUAD(accg, 0, 0, a0, bg); SBE;
    }

    // epilogue: g = gelu_exact(gate) * v * mbias (C/D: col=lane&15, row=quad*4+r)
#pragma unroll
    for (int i = 0; i < 8; ++i) {
        const int mb = m0 + wm * 128 + i * 16 + quad * 4;
#pragma unroll
        for (int j = 0; j < 2; ++j) {
            const int n = n0 + wn * 32 + j * 16 + lo;
            const float mbv = mbias[n];
#pragma unroll
            for (int r = 0; r < 4; ++r) {
                float gt = accg[i][j][r];
                float ge = 0.5f * gt * (1.0f + erff(gt * 0.70710678118654752f));
                pG[(size_t)(mb + r) * DIMH + n] = f2bf(ge * accv[i][j][r] * mbv);
            }
        }
    }
#undef STA1
#undef STBV1
#undef STBG1
}

// ---------------------------------------------------------------------------
// Kernel D: GEMM2. Block tile 256x256, BK=64, K=2048. out scattered to (B,E,CAP,D).
// ---------------------------------------------------------------------------
__global__ __launch_bounds__(512, 2) void gemm2_kernel(
        const unsigned short* __restrict__ gb,   // [z][8192][2048]
        const unsigned short* __restrict__ pT,   // [E][768][2048]
        float* __restrict__ out, int e0) {
    __shared__ __align__(16) unsigned short lds[65536];
    const int t = threadIdx.x;
    const int e = e0 + blockIdx.z;
    const int m0 = blockIdx.x * 256;
    const int n0 = blockIdx.y * 256;
    const unsigned short* pA = gb + (size_t)blockIdx.z * M_TOT * DIMH + (size_t)m0 * DIMH;
    const unsigned short* pB = pT + ((size_t)e * N_EMBD + n0) * DIMH;

    const int sr   = t >> 3;
    const int scs  = ((t & 7) ^ (sr & 7)) * 8;
    const int ldst = t * 8;
    const int lane = t & 63, lo = lane & 15, quad = lane >> 4;
    const int w = t >> 6, wm = w & 1, wn = w >> 1;
    const int sl0 = ((quad    ) ^ (lo & 7)) * 8;
    const int sl1 = ((quad + 4) ^ (lo & 7)) * 8;
    const int aB  = wm * 8192 + lo * 64;
    const int bB  = 16384 + (wn >> 1) * 8192 + ((wn & 1) * 64 + lo) * 64;

#define STA2(D, H, KT)  STG2(pA + (size_t)(H) * 128 * DIMH, DIMH, KT, (D)*32768 + (H)*8192)
#define STB2(D, H, KT)  STG2(pB + (size_t)(H) * 128 * DIMH, DIMH, KT, (D)*32768 + 16384 + (H)*8192)

    f32x4 acc[8][4];
#pragma unroll
    for (int i = 0; i < 8; ++i)
#pragma unroll
        for (int j = 0; j < 4; ++j) acc[i][j] = (f32x4)0.f;
    bf16x8 a0[4][2], a1[4][2], bb[2][2];

    STA2(0, 0, 0); STA2(0, 1, 0); STB2(0, 0, 0); STB2(0, 1, 0); STA2(1, 0, 1);
    VMW(2);
    __builtin_amdgcn_s_barrier();

    for (int it = 0; it < 16; ++it) {                    // 32 K-tiles, 2 per iter
        const int kb = 2 * it + 1, kc = kb + 1, kd = kb + 2;
        const bool more = (it < 15);
        // P1
        RDA4(a0, 0, 0); RDB2(bb, 0, bB);
        STA2(1, 1, kb);
        SBB; QUAD(acc, 0, 0, a0, bb); SBE;
        // P2
        RDA4(a1, 0, 4);
        STB2(1, 0, kb);
        SBB; QUAD(acc, 1, 0, a1, bb); SBE;
        // P3
        RDB2(bb, 0, bB + 2048);
        STB2(1, 1, kb);
        SBB; QUAD(acc, 1, 2, a1, bb); SBE;
        // P4
        if (more) { STA2(0, 0, kc); VMW(2); } else { VMW(0); }
        SBB; QUAD(acc, 0, 2, a0, bb); SBE;
        // P5
        RDA4(a0, 1, 0); RDB2(bb, 1, bB);
        if (more) STA2(0, 1, kc);
        SBB; QUAD(acc, 0, 0, a0, bb); SBE;
        // P6
        RDA4(a1, 1, 4);
        if (more) STB2(0, 0, kc);
        SBB; QUAD(acc, 1, 0, a1, bb); SBE;
        // P7
        RDB2(bb, 1, bB + 2048);
        if (more) STB2(0, 1, kc);
        SBB; QUAD(acc, 1, 2, a1, bb); SBE;
        // P8
        if (more) { STA2(1, 0, kd); VMW(2); } else { VMW(0); }
        SBB; QUAD(acc, 0, 2, a0, bb); SBE;
    }

    // epilogue: scatter fp32 rows to (B, E, CAP, D)
#pragma unroll
    for (int i = 0; i < 8; ++i) {
        const int mb = m0 + wm * 128 + i * 16 + quad * 4;
#pragma unroll
        for (int r = 0; r < 4; ++r) {
            const int m = mb + r;
            const int b = m >> 10, nc = m & 1023;
            float* orow = out + (size_t)((b * N_EXP + e) * CAPN + nc) * N_EMBD;
#pragma unroll
            for (int j = 0; j < 4; ++j)
                orow[n0 + wn * 64 + j * 16 + lo] = acc[i][j][r];
        }
    }
#undef STA2
#undef STB2
}

// ---------------------------------------------------------------------------
extern "C" void kernel_launch(void* const* d_in, const int* in_sizes, int n_in,
                              void* d_out, int out_size, void* d_ws, size_t ws_size,
                              hipStream_t stream) {
    const float* x     = (const float*)d_in[0];
    const float* cfc   = (const float*)d_in[1];
    const float* cproj = (const float*)d_in[2];
    const float* gamma = (const float*)d_in[3];
    const float* mbias = (const float*)d_in[4];
    float* out = (float*)d_out;

    // ws layout (elems, bf16): h [8][8192][768]      = 50331648
    //                          cfcT [8][4096][768]   = 25165824
    //                          cprojT [8][768][2048] = 12582912
    //                          g [z][8192][2048]     = 134217728 (batched) / 16777216 (fallback)
    unsigned short* h      = (unsigned short*)d_ws;
    unsigned short* cfcT   = h + 50331648ull;
    unsigned short* cprojT = cfcT + 25165824ull;
    unsigned short* gbuf   = cprojT + 12582912ull;
    const size_t need_batched = 444596224ull;   // bytes

    norm_convert_kernel<<<dim3(N_EXP * M_TOT), dim3(256), 0, stream>>>(x, gamma, h);
    transpose_convert_kernel<<<dim3(2 * DIMH / 32, N_EMBD / 32, N_EXP), dim3(256), 0, stream>>>(
        cfc, cfcT, N_EMBD, 2 * DIMH);
    transpose_convert_kernel<<<dim3(N_EMBD / 32, DIMH / 32, N_EXP), dim3(256), 0, stream>>>(
        cproj, cprojT, DIMH, N_EMBD);

    if (ws_size >= need_batched) {
        // all experts in one launch each: full chip occupancy, 2 GEMM launches total
        gemm1_kernel<<<dim3(M_TOT / 256, DIMH / 128, N_EXP), dim3(512), 0, stream>>>(
            h, cfcT, mbias, gbuf, 0);
        gemm2_kernel<<<dim3(M_TOT / 256, N_EMBD / 256, N_EXP), dim3(512), 0, stream>>>(
            gbuf, cprojT, out, 0);
    } else {
        // fallback: per-expert loop with single g buffer (209.7 MB total ws)
        for (int e = 0; e < N_EXP; ++e) {
            gemm1_kernel<<<dim3(M_TOT / 256, DIMH / 128, 1), dim3(512), 0, stream>>>(
                h, cfcT, mbias, gbuf, e);
            gemm2_kernel<<<dim3(M_TOT / 256, N_EMBD / 256, 1), dim3(512), 0, stream>>>(
                gbuf, cprojT, out, e);
        }
    }
}

// Round 2
// 1195.716 us; speedup vs baseline: 1.2606x; 1.0565x over previous
//
#include <hip/hip_runtime.h>
#include <math.h>

#define N_EMBD 768
#define N_EXP  8
#define DIMH   2048
#define CAPN   1024
#define M_TOT  8192

typedef __bf16 bf16x8 __attribute__((ext_vector_type(8)));
typedef float  f32x4  __attribute__((ext_vector_type(4)));
typedef unsigned short u16x4 __attribute__((ext_vector_type(4)));

__device__ __forceinline__ unsigned short f2bf(float f) {
    unsigned int u = __float_as_uint(f);
    unsigned int r = (u + 0x7fffu + ((u >> 16) & 1u)) >> 16;
    return (unsigned short)r;
}

__device__ __forceinline__ void gload16(const void* g, void* l) {
    __builtin_amdgcn_global_load_lds(
        (const __attribute__((address_space(1))) unsigned int*)g,
        (__attribute__((address_space(3))) unsigned int*)l, 16, 0, 0);
}

// branch-free exact-gelu: erf via A&S 7.1.26 (|err|<1.5e-7, sub-bf16-ulp)
__device__ __forceinline__ float gelu_exact(float x) {
    float ax = fabsf(x);
    float z  = ax * 0.70710678118654752f;
    float t  = __builtin_amdgcn_rcpf(fmaf(0.3275911f, z, 1.0f));
    float p  = fmaf(t, 1.061405429f, -1.453152027f);
    p = fmaf(p, t, 1.421413741f);
    p = fmaf(p, t, -0.284496736f);
    p = fmaf(p, t, 0.254829592f);
    p = p * t;
    float ez = __expf(-z * z);
    float erfz = fmaf(-p, ez, 1.0f);      // erf(|x|/sqrt2)
    return 0.5f * fmaf(ax, erfz, x);      // 0.5*(x + |x|*erf(z))
}

// ---------------------------------------------------------------------------
// Kernel A: per-row L2 norm + scale + gamma + fp32->bf16.  One WAVE per row.
// float4 loads (16B/lane), ushort4 stores (8B/lane), xor-butterfly reduce.
// ---------------------------------------------------------------------------
__global__ __launch_bounds__(256) void norm_convert_kernel(
        const float* __restrict__ x, const float* __restrict__ gamma,
        unsigned short* __restrict__ h) {
    int r = (blockIdx.x << 2) | (threadIdx.x >> 6);   // row 0..65535
    int lane = threadIdx.x & 63;
    int e = r >> 13, m = r & 8191;
    int b = m >> 10, nc = m & 1023;
    const float4* row = (const float4*)(x + (size_t)((b * N_EXP + e) * CAPN + nc) * N_EMBD);
    const float4* g4  = (const float4*)gamma;

    float4 v0 = row[lane], v1 = row[lane + 64], v2 = row[lane + 128];
    float acc = v0.x*v0.x + v0.y*v0.y + v0.z*v0.z + v0.w*v0.w
              + v1.x*v1.x + v1.y*v1.y + v1.z*v1.z + v1.w*v1.w
              + v2.x*v2.x + v2.y*v2.y + v2.z*v2.z + v2.w*v2.w;
#pragma unroll
    for (int off = 32; off >= 1; off >>= 1) acc += __shfl_xor(acc, off, 64);
    float s = 27.712812921102035f / fmaxf(sqrtf(acc), 1e-12f);

    float4 g0 = g4[lane], g1 = g4[lane + 64], g2 = g4[lane + 128];
    u16x4* o4 = (u16x4*)(h + (size_t)(e * M_TOT + m) * N_EMBD);
    u16x4 o;
    o[0]=f2bf(v0.x*s*g0.x); o[1]=f2bf(v0.y*s*g0.y); o[2]=f2bf(v0.z*s*g0.z); o[3]=f2bf(v0.w*s*g0.w);
    o4[lane] = o;
    o[0]=f2bf(v1.x*s*g1.x); o[1]=f2bf(v1.y*s*g1.y); o[2]=f2bf(v1.z*s*g1.z); o[3]=f2bf(v1.w*s*g1.w);
    o4[lane + 64] = o;
    o[0]=f2bf(v2.x*s*g2.x); o[1]=f2bf(v2.y*s*g2.y); o[2]=f2bf(v2.z*s*g2.z); o[3]=f2bf(v2.w*s*g2.w);
    o4[lane + 128] = o;
}

// ---------------------------------------------------------------------------
// Kernel B: transpose + convert weights. in: [z][R][C] fp32 -> out: [z][C][R] bf16
// ---------------------------------------------------------------------------
__global__ __launch_bounds__(256) void transpose_convert_kernel(
        const float* __restrict__ in, unsigned short* __restrict__ out, int R, int C) {
    __shared__ float tile[32][33];
    int c0 = blockIdx.x * 32, r0 = blockIdx.y * 32;
    const float* ip = in + (size_t)blockIdx.z * R * C;
    unsigned short* op = out + (size_t)blockIdx.z * R * C;
    int tx = threadIdx.x & 31, ty = threadIdx.x >> 5;
#pragma unroll
    for (int i = 0; i < 4; ++i)
        tile[ty + 8 * i][tx] = ip[(size_t)(r0 + ty + 8 * i) * C + c0 + tx];
    __syncthreads();
#pragma unroll
    for (int i = 0; i < 4; ++i)
        op[(size_t)(c0 + ty + 8 * i) * R + r0 + tx] = f2bf(tile[tx][ty + 8 * i]);
}

// ---------------------------------------------------------------------------
// 8-phase 256-row GEMM machinery.
// Deep prefetch: ALL 8 gload_lds of tile t+1 are issued in P1 (its dbuf is
// freed by the P8 barrier of the previous iteration); the VMW(0) gate sits at
// P4-start, 3 phases (~1000cy) after issue. t+2 staged in P5, gated at P8.
// vmcnt gate is always followed by a barrier before dependent ds_reads.
// ---------------------------------------------------------------------------
#define SBB  __builtin_amdgcn_s_barrier(); \
             asm volatile("s_waitcnt lgkmcnt(0)" ::: "memory"); \
             __builtin_amdgcn_sched_barrier(0); \
             __builtin_amdgcn_s_setprio(1)
#define SBE  __builtin_amdgcn_s_setprio(0); __builtin_amdgcn_s_barrier()
#define VMW0 do { asm volatile("s_waitcnt vmcnt(0)" ::: "memory"); \
             __builtin_amdgcn_sched_barrier(0); } while (0)

// stage one 128x64 half-tile: 512 thr x 2 loads x 16B; linear LDS dest,
// inverse-swizzled global source. KO = k offset in elements.
#define STG2(PSRC, RS, KO, DOFF) do { \
    gload16((PSRC) + (size_t)sr * (RS) + (KO) + scs, lds + (DOFF) + ldst); \
    gload16((PSRC) + (size_t)(sr + 64) * (RS) + (KO) + scs, lds + (DOFF) + ldst + 4096); \
  } while (0)

#define RDF(V) (*(const bf16x8*)(lds + (V)))

#define RDA4(AF, DB, IB) do { \
    _Pragma("unroll") for (int i_ = 0; i_ < 4; ++i_) { \
      AF[i_][0] = RDF((DB)*32768 + aB + ((IB) + i_)*1024 + sl0); \
      AF[i_][1] = RDF((DB)*32768 + aB + ((IB) + i_)*1024 + sl1); } \
  } while (0)

#define RDB2(BF, DB, BASE) do { \
    _Pragma("unroll") for (int j_ = 0; j_ < 2; ++j_) { \
      BF[j_][0] = RDF((DB)*32768 + (BASE) + j_*1024 + sl0); \
      BF[j_][1] = RDF((DB)*32768 + (BASE) + j_*1024 + sl1); } \
  } while (0)

#define QUAD(ACC, MS, NB, AF, BF) do { \
    _Pragma("unroll") for (int i_ = 0; i_ < 4; ++i_) \
    _Pragma("unroll") for (int j_ = 0; j_ < 2; ++j_) { \
      ACC[(MS)*4 + i_][(NB) + j_] = __builtin_amdgcn_mfma_f32_16x16x32_bf16( \
          AF[i_][0], BF[j_][0], ACC[(MS)*4 + i_][(NB) + j_], 0, 0, 0); \
      ACC[(MS)*4 + i_][(NB) + j_] = __builtin_amdgcn_mfma_f32_16x16x32_bf16( \
          AF[i_][1], BF[j_][1], ACC[(MS)*4 + i_][(NB) + j_], 0, 0, 0); } \
  } while (0)

// ---------------------------------------------------------------------------
// Kernel C: GEMM1 + GLU epilogue. Block tile: 256(M) x 128(g-cols), BK=64.
// ---------------------------------------------------------------------------
__global__ __launch_bounds__(512, 2) void gemm1_kernel(
        const unsigned short* __restrict__ hb,   // [E][8192][768]
        const unsigned short* __restrict__ fT,   // [E][4096][768]
        const float* __restrict__ mbias,         // [2048]
        unsigned short* __restrict__ gb,         // [z][8192][2048]
        int e0) {
    __shared__ __align__(16) unsigned short lds[65536];   // 128 KiB
    const int t = threadIdx.x;
    const int e = e0 + blockIdx.z;
    const int m0 = blockIdx.x * 256;
    const int n0 = blockIdx.y * 128;
    const unsigned short* pA  = hb + ((size_t)e * M_TOT + m0) * N_EMBD;
    const unsigned short* pBv = fT + ((size_t)e * 2 * DIMH + n0) * N_EMBD;
    const unsigned short* pBg = pBv + (size_t)DIMH * N_EMBD;
    unsigned short* pG = gb + (size_t)blockIdx.z * M_TOT * DIMH;

    const int sr   = t >> 3;
    const int scs  = ((t & 7) ^ (sr & 7)) * 8;
    const int ldst = t * 8;
    const int lane = t & 63, lo = lane & 15, quad = lane >> 4;
    const int w = t >> 6, wm = w & 1, wn = w >> 1;
    const int sl0 = ((quad    ) ^ (lo & 7)) * 8;
    const int sl1 = ((quad + 4) ^ (lo & 7)) * 8;
    const int aB  = wm * 8192 + lo * 64;
    const int bvB = 16384 + (wn * 32 + lo) * 64;
    const int bgB = 24576 + (wn * 32 + lo) * 64;

#define STA1(D, H, KO)  STG2(pA + (size_t)(H) * 128 * N_EMBD, N_EMBD, KO, (D)*32768 + (H)*8192)
#define STBV1(D, KO)    STG2(pBv, N_EMBD, KO, (D)*32768 + 16384)
#define STBG1(D, KO)    STG2(pBg, N_EMBD, KO, (D)*32768 + 24576)
#define STALL1(D, KO)   do { STA1(D,0,KO); STA1(D,1,KO); STBV1(D,KO); STBG1(D,KO); } while (0)

    f32x4 accv[8][2], accg[8][2];
#pragma unroll
    for (int i = 0; i < 8; ++i)
#pragma unroll
        for (int j = 0; j < 2; ++j) { accv[i][j] = (f32x4)0.f; accg[i][j] = (f32x4)0.f; }
    bf16x8 a0[4][2], a1[4][2], bv[2][2], bg[2][2];

    // prologue: stage tile 0 -> dbuf0, drain, sync
    STALL1(0, 0);
    VMW0;
    __builtin_amdgcn_s_barrier();

    int ko = 64;
    for (int it = 0; it < 6; ++it) {                 // 12 K-tiles, 2 per iter
        const bool more = (it < 5);
        // P1: stage FULL tile t+1 -> d1 (8 loads); read d0 A0-3 + Bv
        STALL1(1, ko);
        RDA4(a0, 0, 0); RDB2(bv, 0, bvB);
        SBB; QUAD(accv, 0, 0, a0, bv); SBE;
        // P2
        RDA4(a1, 0, 4);
        SBB; QUAD(accv, 1, 0, a1, bv); SBE;
        // P3
        RDB2(bg, 0, bgB);
        SBB; QUAD(accg, 1, 0, a1, bg); SBE;
        // P4: gate on t+1 (issued P1, ~3 phases of cover)
        VMW0;
        SBB; QUAD(accg, 0, 0, a0, bg); SBE;
        // P5: stage FULL tile t+2 -> d0; read d1
        if (more) STALL1(0, ko + 64);
        RDA4(a0, 1, 0); RDB2(bv, 1, bvB);
        SBB; QUAD(accv, 0, 0, a0, bv); SBE;
        // P6
        RDA4(a1, 1, 4);
        SBB; QUAD(accv, 1, 0, a1, bv); SBE;
        // P7
        RDB2(bg, 1, bgB);
        SBB; QUAD(accg, 1, 0, a1, bg); SBE;
        // P8: gate on t+2 (issued P5)
        VMW0;
        SBB; QUAD(accg, 0, 0, a0, bg); SBE;
        ko += 128;
    }

    // epilogue: g = gelu_exact(gate) * v * mbias (C/D: col=lane&15, row=quad*4+r)
#pragma unroll
    for (int i = 0; i < 8; ++i) {
        const int mb = m0 + wm * 128 + i * 16 + quad * 4;
#pragma unroll
        for (int j = 0; j < 2; ++j) {
            const int n = n0 + wn * 32 + j * 16 + lo;
            const float mbv = mbias[n];
#pragma unroll
            for (int r = 0; r < 4; ++r) {
                float ge = gelu_exact(accg[i][j][r]);
                pG[(size_t)(mb + r) * DIMH + n] = f2bf(ge * accv[i][j][r] * mbv);
            }
        }
    }
#undef STA1
#undef STBV1
#undef STBG1
#undef STALL1
}

// ---------------------------------------------------------------------------
// Kernel D: GEMM2. Block tile 256x256, BK=64, K=2048. out scattered to (B,E,CAP,D).
// ---------------------------------------------------------------------------
__global__ __launch_bounds__(512, 2) void gemm2_kernel(
        const unsigned short* __restrict__ gb,   // [z][8192][2048]
        const unsigned short* __restrict__ pT,   // [E][768][2048]
        float* __restrict__ out, int e0) {
    __shared__ __align__(16) unsigned short lds[65536];
    const int t = threadIdx.x;
    const int e = e0 + blockIdx.z;
    const int m0 = blockIdx.x * 256;
    const int n0 = blockIdx.y * 256;
    const unsigned short* pA = gb + (size_t)blockIdx.z * M_TOT * DIMH + (size_t)m0 * DIMH;
    const unsigned short* pB = pT + ((size_t)e * N_EMBD + n0) * DIMH;

    const int sr   = t >> 3;
    const int scs  = ((t & 7) ^ (sr & 7)) * 8;
    const int ldst = t * 8;
    const int lane = t & 63, lo = lane & 15, quad = lane >> 4;
    const int w = t >> 6, wm = w & 1, wn = w >> 1;
    const int sl0 = ((quad    ) ^ (lo & 7)) * 8;
    const int sl1 = ((quad + 4) ^ (lo & 7)) * 8;
    const int aB  = wm * 8192 + lo * 64;
    const int bB  = 16384 + (wn >> 1) * 8192 + ((wn & 1) * 64 + lo) * 64;

#define STA2(D, H, KO)  STG2(pA + (size_t)(H) * 128 * DIMH, DIMH, KO, (D)*32768 + (H)*8192)
#define STB2(D, H, KO)  STG2(pB + (size_t)(H) * 128 * DIMH, DIMH, KO, (D)*32768 + 16384 + (H)*8192)
#define STALL2(D, KO)   do { STA2(D,0,KO); STA2(D,1,KO); STB2(D,0,KO); STB2(D,1,KO); } while (0)

    f32x4 acc[8][4];
#pragma unroll
    for (int i = 0; i < 8; ++i)
#pragma unroll
        for (int j = 0; j < 4; ++j) acc[i][j] = (f32x4)0.f;
    bf16x8 a0[4][2], a1[4][2], bb[2][2];

    STALL2(0, 0);
    VMW0;
    __builtin_amdgcn_s_barrier();

    int ko = 64;
    for (int it = 0; it < 16; ++it) {                // 32 K-tiles, 2 per iter
        const bool more = (it < 15);
        // P1: stage FULL tile t+1 -> d1; read d0
        STALL2(1, ko);
        RDA4(a0, 0, 0); RDB2(bb, 0, bB);
        SBB; QUAD(acc, 0, 0, a0, bb); SBE;
        // P2
        RDA4(a1, 0, 4);
        SBB; QUAD(acc, 1, 0, a1, bb); SBE;
        // P3
        RDB2(bb, 0, bB + 2048);
        SBB; QUAD(acc, 1, 2, a1, bb); SBE;
        // P4: gate on t+1
        VMW0;
        SBB; QUAD(acc, 0, 2, a0, bb); SBE;
        // P5: stage FULL tile t+2 -> d0; read d1
        if (more) STALL2(0, ko + 64);
        RDA4(a0, 1, 0); RDB2(bb, 1, bB);
        SBB; QUAD(acc, 0, 0, a0, bb); SBE;
        // P6
        RDA4(a1, 1, 4);
        SBB; QUAD(acc, 1, 0, a1, bb); SBE;
        // P7
        RDB2(bb, 1, bB + 2048);
        SBB; QUAD(acc, 1, 2, a1, bb); SBE;
        // P8: gate on t+2
        VMW0;
        SBB; QUAD(acc, 0, 2, a0, bb); SBE;
        ko += 128;
    }

    // epilogue: scatter fp32 rows to (B, E, CAP, D)
#pragma unroll
    for (int i = 0; i < 8; ++i) {
        const int mb = m0 + wm * 128 + i * 16 + quad * 4;
#pragma unroll
        for (int r = 0; r < 4; ++r) {
            const int m = mb + r;
            const int b = m >> 10, nc = m & 1023;
            float* orow = out + (size_t)((b * N_EXP + e) * CAPN + nc) * N_EMBD;
#pragma unroll
            for (int j = 0; j < 4; ++j)
                orow[n0 + wn * 64 + j * 16 + lo] = acc[i][j][r];
        }
    }
#undef STA2
#undef STB2
#undef STALL2
}

// ---------------------------------------------------------------------------
extern "C" void kernel_launch(void* const* d_in, const int* in_sizes, int n_in,
                              void* d_out, int out_size, void* d_ws, size_t ws_size,
                              hipStream_t stream) {
    const float* x     = (const float*)d_in[0];
    const float* cfc   = (const float*)d_in[1];
    const float* cproj = (const float*)d_in[2];
    const float* gamma = (const float*)d_in[3];
    const float* mbias = (const float*)d_in[4];
    float* out = (float*)d_out;

    unsigned short* h      = (unsigned short*)d_ws;
    unsigned short* cfcT   = h + 50331648ull;
    unsigned short* cprojT = cfcT + 25165824ull;
    unsigned short* gbuf   = cprojT + 12582912ull;
    const size_t need_batched = 444596224ull;   // bytes

    norm_convert_kernel<<<dim3(N_EXP * M_TOT / 4), dim3(256), 0, stream>>>(x, gamma, h);
    transpose_convert_kernel<<<dim3(2 * DIMH / 32, N_EMBD / 32, N_EXP), dim3(256), 0, stream>>>(
        cfc, cfcT, N_EMBD, 2 * DIMH);
    transpose_convert_kernel<<<dim3(N_EMBD / 32, DIMH / 32, N_EXP), dim3(256), 0, stream>>>(
        cproj, cprojT, DIMH, N_EMBD);

    if (ws_size >= need_batched) {
        gemm1_kernel<<<dim3(M_TOT / 256, DIMH / 128, N_EXP), dim3(512), 0, stream>>>(
            h, cfcT, mbias, gbuf, 0);
        gemm2_kernel<<<dim3(M_TOT / 256, N_EMBD / 256, N_EXP), dim3(512), 0, stream>>>(
            gbuf, cprojT, out, 0);
    } else {
        for (int e = 0; e < N_EXP; ++e) {
            gemm1_kernel<<<dim3(M_TOT / 256, DIMH / 128, 1), dim3(512), 0, stream>>>(
                h, cfcT, mbias, gbuf, e);
            gemm2_kernel<<<dim3(M_TOT / 256, N_EMBD / 256, 1), dim3(512), 0, stream>>>(
                gbuf, cprojT, out, e);
        }
    }
}

// Round 3
// 1106.483 us; speedup vs baseline: 1.3623x; 1.0806x over previous
//
#include <hip/hip_runtime.h>
#include <math.h>

#define N_EMBD 768
#define N_EXP  8
#define DIMH   2048
#define CAPN   1024
#define M_TOT  8192

typedef __bf16 bf16x8 __attribute__((ext_vector_type(8)));
typedef float  f32x4  __attribute__((ext_vector_type(4)));
typedef unsigned short u16x4 __attribute__((ext_vector_type(4)));

__device__ __forceinline__ unsigned short f2bf(float f) {
    unsigned int u = __float_as_uint(f);
    unsigned int r = (u + 0x7fffu + ((u >> 16) & 1u)) >> 16;
    return (unsigned short)r;
}

__device__ __forceinline__ void gload16(const void* g, void* l) {
    __builtin_amdgcn_global_load_lds(
        (const __attribute__((address_space(1))) unsigned int*)g,
        (__attribute__((address_space(3))) unsigned int*)l, 16, 0, 0);
}

// branch-free exact-gelu: erf via A&S 7.1.26 (|err|<1.5e-7, sub-bf16-ulp)
__device__ __forceinline__ float gelu_exact(float x) {
    float ax = fabsf(x);
    float z  = ax * 0.70710678118654752f;
    float t  = __builtin_amdgcn_rcpf(fmaf(0.3275911f, z, 1.0f));
    float p  = fmaf(t, 1.061405429f, -1.453152027f);
    p = fmaf(p, t, 1.421413741f);
    p = fmaf(p, t, -0.284496736f);
    p = fmaf(p, t, 0.254829592f);
    p = p * t;
    float ez = __expf(-z * z);
    float erfz = fmaf(-p, ez, 1.0f);
    return 0.5f * fmaf(ax, erfz, x);
}

// ---------------------------------------------------------------------------
// Kernel A: per-row L2 norm + scale + gamma + fp32->bf16.  One WAVE per row.
// ---------------------------------------------------------------------------
__global__ __launch_bounds__(256) void norm_convert_kernel(
        const float* __restrict__ x, const float* __restrict__ gamma,
        unsigned short* __restrict__ h) {
    int r = (blockIdx.x << 2) | (threadIdx.x >> 6);   // row 0..65535
    int lane = threadIdx.x & 63;
    int e = r >> 13, m = r & 8191;
    int b = m >> 10, nc = m & 1023;
    const float4* row = (const float4*)(x + (size_t)((b * N_EXP + e) * CAPN + nc) * N_EMBD);
    const float4* g4  = (const float4*)gamma;

    float4 v0 = row[lane], v1 = row[lane + 64], v2 = row[lane + 128];
    float acc = v0.x*v0.x + v0.y*v0.y + v0.z*v0.z + v0.w*v0.w
              + v1.x*v1.x + v1.y*v1.y + v1.z*v1.z + v1.w*v1.w
              + v2.x*v2.x + v2.y*v2.y + v2.z*v2.z + v2.w*v2.w;
#pragma unroll
    for (int off = 32; off >= 1; off >>= 1) acc += __shfl_xor(acc, off, 64);
    float s = 27.712812921102035f / fmaxf(sqrtf(acc), 1e-12f);

    float4 g0 = g4[lane], g1 = g4[lane + 64], g2 = g4[lane + 128];
    u16x4* o4 = (u16x4*)(h + (size_t)(e * M_TOT + m) * N_EMBD);
    u16x4 o;
    o[0]=f2bf(v0.x*s*g0.x); o[1]=f2bf(v0.y*s*g0.y); o[2]=f2bf(v0.z*s*g0.z); o[3]=f2bf(v0.w*s*g0.w);
    o4[lane] = o;
    o[0]=f2bf(v1.x*s*g1.x); o[1]=f2bf(v1.y*s*g1.y); o[2]=f2bf(v1.z*s*g1.z); o[3]=f2bf(v1.w*s*g1.w);
    o4[lane + 64] = o;
    o[0]=f2bf(v2.x*s*g2.x); o[1]=f2bf(v2.y*s*g2.y); o[2]=f2bf(v2.z*s*g2.z); o[3]=f2bf(v2.w*s*g2.w);
    o4[lane + 128] = o;
}

// ---------------------------------------------------------------------------
// Kernel B: transpose + convert weights. in: [z][R][C] fp32 -> out: [z][C][R] bf16
// ---------------------------------------------------------------------------
__global__ __launch_bounds__(256) void transpose_convert_kernel(
        const float* __restrict__ in, unsigned short* __restrict__ out, int R, int C) {
    __shared__ float tile[32][33];
    int c0 = blockIdx.x * 32, r0 = blockIdx.y * 32;
    const float* ip = in + (size_t)blockIdx.z * R * C;
    unsigned short* op = out + (size_t)blockIdx.z * R * C;
    int tx = threadIdx.x & 31, ty = threadIdx.x >> 5;
#pragma unroll
    for (int i = 0; i < 4; ++i)
        tile[ty + 8 * i][tx] = ip[(size_t)(r0 + ty + 8 * i) * C + c0 + tx];
    __syncthreads();
#pragma unroll
    for (int i = 0; i < 4; ++i)
        op[(size_t)(c0 + ty + 8 * i) * R + r0 + tx] = f2bf(tile[tx][ty + 8 * i]);
}

// ---------------------------------------------------------------------------
// 8-phase 256-row GEMM machinery — COUNTED vmcnt schedule (T3+T4+T5).
// Exactly one half-tile (2 gloads/thread) staged per phase; gates force only
// the oldest loads (in-order vmcnt retirement), 4-8 loads always in flight.
// Region-restage safety: every LDS region is restaged >=1 barrier after its
// last ds_read (reads drained by SBB's lgkmcnt + SBE barrier).
// ---------------------------------------------------------------------------
#define SBB  __builtin_amdgcn_s_barrier(); \
             asm volatile("s_waitcnt lgkmcnt(0)" ::: "memory"); \
             __builtin_amdgcn_sched_barrier(0); \
             __builtin_amdgcn_s_setprio(1)
#define SBE  __builtin_amdgcn_s_setprio(0); __builtin_amdgcn_s_barrier()
#define VMW(N) do { asm volatile("s_waitcnt vmcnt(" #N ")" ::: "memory"); \
             __builtin_amdgcn_sched_barrier(0); } while (0)

// stage one 128x64 half-tile: 512 thr x 2 loads x 16B; linear LDS dest,
// inverse-swizzled global source. KO = k offset in elements.
#define STG2(PSRC, RS, KO, DOFF) do { \
    gload16((PSRC) + (size_t)sr * (RS) + (KO) + scs, lds + (DOFF) + ldst); \
    gload16((PSRC) + (size_t)(sr + 64) * (RS) + (KO) + scs, lds + (DOFF) + ldst + 4096); \
  } while (0)

#define RDF(V) (*(const bf16x8*)(lds + (V)))

#define RDA4(AF, DB, IB) do { \
    _Pragma("unroll") for (int i_ = 0; i_ < 4; ++i_) { \
      AF[i_][0] = RDF((DB)*32768 + aB + ((IB) + i_)*1024 + sl0); \
      AF[i_][1] = RDF((DB)*32768 + aB + ((IB) + i_)*1024 + sl1); } \
  } while (0)

#define RDB2(BF, DB, BASE) do { \
    _Pragma("unroll") for (int j_ = 0; j_ < 2; ++j_) { \
      BF[j_][0] = RDF((DB)*32768 + (BASE) + j_*1024 + sl0); \
      BF[j_][1] = RDF((DB)*32768 + (BASE) + j_*1024 + sl1); } \
  } while (0)

#define QUAD(ACC, MS, NB, AF, BF) do { \
    _Pragma("unroll") for (int i_ = 0; i_ < 4; ++i_) \
    _Pragma("unroll") for (int j_ = 0; j_ < 2; ++j_) { \
      ACC[(MS)*4 + i_][(NB) + j_] = __builtin_amdgcn_mfma_f32_16x16x32_bf16( \
          AF[i_][0], BF[j_][0], ACC[(MS)*4 + i_][(NB) + j_], 0, 0, 0); \
      ACC[(MS)*4 + i_][(NB) + j_] = __builtin_amdgcn_mfma_f32_16x16x32_bf16( \
          AF[i_][1], BF[j_][1], ACC[(MS)*4 + i_][(NB) + j_], 0, 0, 0); } \
  } while (0)

// ---------------------------------------------------------------------------
// Kernel C: GEMM1 + GLU epilogue. Block tile: 256(M) x 128(g-cols), BK=64.
// Stage map (iter J; E=2J in d0, O=2J+1 in d1): P1:O.Bg  P2:E'.Bv  P3:E'.A0
// P4:E'.A1  P5:E'.Bg  P6:O'.Bv  P7:O'.A0  P8:O'.A1   (E'=2J+2, O'=2J+3)
// Gates: P2 vmcnt(8); P4 vmcnt(6) [tail: 2]; P6 tail-only vmcnt(0); P8 vmcnt(8).
// ---------------------------------------------------------------------------
__global__ __launch_bounds__(512, 2) void gemm1_kernel(
        const unsigned short* __restrict__ hb,   // [E][8192][768]
        const unsigned short* __restrict__ fT,   // [E][4096][768]
        const float* __restrict__ mbias,         // [2048]
        unsigned short* __restrict__ gb,         // [z][8192][2048]
        int e0) {
    __shared__ __align__(16) unsigned short lds[65536];   // 128 KiB
    const int t = threadIdx.x;
    const int e = e0 + blockIdx.z;
    const int m0 = blockIdx.x * 256;
    const int n0 = blockIdx.y * 128;
    const unsigned short* pA  = hb + ((size_t)e * M_TOT + m0) * N_EMBD;
    const unsigned short* pBv = fT + ((size_t)e * 2 * DIMH + n0) * N_EMBD;
    const unsigned short* pBg = pBv + (size_t)DIMH * N_EMBD;
    unsigned short* pG = gb + (size_t)blockIdx.z * M_TOT * DIMH;

    const int sr   = t >> 3;
    const int scs  = ((t & 7) ^ (sr & 7)) * 8;
    const int ldst = t * 8;
    const int lane = t & 63, lo = lane & 15, quad = lane >> 4;
    const int w = t >> 6, wm = w & 1, wn = w >> 1;
    const int sl0 = ((quad    ) ^ (lo & 7)) * 8;
    const int sl1 = ((quad + 4) ^ (lo & 7)) * 8;
    const int aB  = wm * 8192 + lo * 64;
    const int bvB = 16384 + (wn * 32 + lo) * 64;
    const int bgB = 24576 + (wn * 32 + lo) * 64;

#define STA1(D, H, KO)  STG2(pA + (size_t)(H) * 128 * N_EMBD, N_EMBD, KO, (D)*32768 + (H)*8192)
#define STBV1(D, KO)    STG2(pBv, N_EMBD, KO, (D)*32768 + 16384)
#define STBG1(D, KO)    STG2(pBg, N_EMBD, KO, (D)*32768 + 24576)

    f32x4 accv[8][2], accg[8][2];
#pragma unroll
    for (int i = 0; i < 8; ++i)
#pragma unroll
        for (int j = 0; j < 2; ++j) { accv[i][j] = (f32x4)0.f; accg[i][j] = (f32x4)0.f; }
    bf16x8 a0[4][2], a1[4][2], bv[2][2], bg[2][2];

    // prologue: t0 full + t1.{Bv,A0,A1}; force t0 (leave 6 in flight)
    STBV1(0, 0); STA1(0, 0, 0); STA1(0, 1, 0); STBG1(0, 0);
    STBV1(1, 64); STA1(1, 0, 64); STA1(1, 1, 64);
    VMW(6);
    __builtin_amdgcn_s_barrier();

    for (int it = 0; it < 6; ++it) {                 // 12 K-tiles, 2 per iter
        const bool more = (it < 5);
        const int koO  = it * 128 + 64;              // tile 2it+1
        const int koE2 = it * 128 + 128;             // tile 2it+2
        const int koO2 = it * 128 + 192;             // tile 2it+3
        // P1: read E.a0+Bv; stage O.Bg
        RDA4(a0, 0, 0); RDB2(bv, 0, bvB);
        STBG1(1, koO);
        SBB; QUAD(accv, 0, 0, a0, bv); SBE;
        // P2: read E.a1; stage E'.Bv; gate (forces E.Bg & older)
        RDA4(a1, 0, 4);
        if (more) STBV1(0, koE2);
        VMW(8);
        SBB; QUAD(accv, 1, 0, a1, bv); SBE;
        // P3: read E.Bg; stage E'.A0
        RDB2(bg, 0, bgB);
        if (more) STA1(0, 0, koE2);
        SBB; QUAD(accg, 1, 0, a1, bg); SBE;
        // P4: stage E'.A1; gate (forces O.{Bv,A0,A1,Bg})
        if (more) { STA1(0, 1, koE2); VMW(6); } else { VMW(2); }
        SBB; QUAD(accg, 0, 0, a0, bg); SBE;
        // P5: read O.a0+Bv; stage E'.Bg
        RDA4(a0, 1, 0); RDB2(bv, 1, bvB);
        if (more) STBG1(0, koE2);
        SBB; QUAD(accv, 0, 0, a0, bv); SBE;
        // P6: read O.a1; stage O'.Bv (tail: drain O.Bg)
        RDA4(a1, 1, 4);
        if (more) STBV1(1, koO2); else VMW(0);
        SBB; QUAD(accv, 1, 0, a1, bv); SBE;
        // P7: read O.Bg; stage O'.A0
        RDB2(bg, 1, bgB);
        if (more) STA1(1, 0, koO2);
        SBB; QUAD(accg, 1, 0, a1, bg); SBE;
        // P8: stage O'.A1; gate (forces E'.{Bv,A0,A1})
        if (more) { STA1(1, 1, koO2); VMW(8); }
        SBB; QUAD(accg, 0, 0, a0, bg); SBE;
    }

    // epilogue: g = gelu_exact(gate) * v * mbias (C/D: col=lane&15, row=quad*4+r)
#pragma unroll
    for (int i = 0; i < 8; ++i) {
        const int mb = m0 + wm * 128 + i * 16 + quad * 4;
#pragma unroll
        for (int j = 0; j < 2; ++j) {
            const int n = n0 + wn * 32 + j * 16 + lo;
            const float mbv = mbias[n];
#pragma unroll
            for (int r = 0; r < 4; ++r) {
                float ge = gelu_exact(accg[i][j][r]);
                pG[(size_t)(mb + r) * DIMH + n] = f2bf(ge * accv[i][j][r] * mbv);
            }
        }
    }
#undef STA1
#undef STBV1
#undef STBG1
}

// ---------------------------------------------------------------------------
// Kernel D: GEMM2. Block tile 256x256, BK=64, K=2048.
// Stage map (iter J): P1:O.B0  P2:O.B1  P3:E'.A0  P4:E'.A1  P5:E'.B0
// P6:E'.B1  P7:O'.A0  P8:O'.A1.  Gates: P4 vmcnt(4) [tail: 0]; P8 vmcnt(4).
// ---------------------------------------------------------------------------
__global__ __launch_bounds__(512, 2) void gemm2_kernel(
        const unsigned short* __restrict__ gb,   // [z][8192][2048]
        const unsigned short* __restrict__ pT,   // [E][768][2048]
        float* __restrict__ out, int e0) {
    __shared__ __align__(16) unsigned short lds[65536];
    const int t = threadIdx.x;
    const int e = e0 + blockIdx.z;
    const int m0 = blockIdx.x * 256;
    const int n0 = blockIdx.y * 256;
    const unsigned short* pA = gb + (size_t)blockIdx.z * M_TOT * DIMH + (size_t)m0 * DIMH;
    const unsigned short* pB = pT + ((size_t)e * N_EMBD + n0) * DIMH;

    const int sr   = t >> 3;
    const int scs  = ((t & 7) ^ (sr & 7)) * 8;
    const int ldst = t * 8;
    const int lane = t & 63, lo = lane & 15, quad = lane >> 4;
    const int w = t >> 6, wm = w & 1, wn = w >> 1;
    const int sl0 = ((quad    ) ^ (lo & 7)) * 8;
    const int sl1 = ((quad + 4) ^ (lo & 7)) * 8;
    const int aB  = wm * 8192 + lo * 64;
    const int bB  = 16384 + (wn >> 1) * 8192 + ((wn & 1) * 64 + lo) * 64;

#define STA2(D, H, KO)  STG2(pA + (size_t)(H) * 128 * DIMH, DIMH, KO, (D)*32768 + (H)*8192)
#define STB2(D, H, KO)  STG2(pB + (size_t)(H) * 128 * DIMH, DIMH, KO, (D)*32768 + 16384 + (H)*8192)

    f32x4 acc[8][4];
#pragma unroll
    for (int i = 0; i < 8; ++i)
#pragma unroll
        for (int j = 0; j < 4; ++j) acc[i][j] = (f32x4)0.f;
    bf16x8 a0[4][2], a1[4][2], bb[2][2];

    // prologue: t0 full + t1.{A0,A1}; force t0 (leave 4 in flight)
    STA2(0, 0, 0); STA2(0, 1, 0); STB2(0, 0, 0); STB2(0, 1, 0);
    STA2(1, 0, 64); STA2(1, 1, 64);
    VMW(4);
    __builtin_amdgcn_s_barrier();

    for (int it = 0; it < 16; ++it) {                // 32 K-tiles, 2 per iter
        const bool more = (it < 15);
        const int koO  = it * 128 + 64;              // tile 2it+1
        const int koE2 = it * 128 + 128;             // tile 2it+2
        const int koO2 = it * 128 + 192;             // tile 2it+3
        // P1: read E.a0+B(lo); stage O.B0
        RDA4(a0, 0, 0); RDB2(bb, 0, bB);
        STB2(1, 0, koO);
        SBB; QUAD(acc, 0, 0, a0, bb); SBE;
        // P2: read E.a1; stage O.B1
        RDA4(a1, 0, 4);
        STB2(1, 1, koO);
        SBB; QUAD(acc, 1, 0, a1, bb); SBE;
        // P3: read E.B(hi); stage E'.A0
        RDB2(bb, 0, bB + 2048);
        if (more) STA2(0, 0, koE2);
        SBB; QUAD(acc, 1, 2, a1, bb); SBE;
        // P4: stage E'.A1; gate (forces O complete)
        if (more) { STA2(0, 1, koE2); VMW(4); } else { VMW(0); }
        SBB; QUAD(acc, 0, 2, a0, bb); SBE;
        // P5: read O.a0+B(lo); stage E'.B0
        RDA4(a0, 1, 0); RDB2(bb, 1, bB);
        if (more) STB2(0, 0, koE2);
        SBB; QUAD(acc, 0, 0, a0, bb); SBE;
        // P6: read O.a1; stage E'.B1
        RDA4(a1, 1, 4);
        if (more) STB2(0, 1, koE2);
        SBB; QUAD(acc, 1, 0, a1, bb); SBE;
        // P7: read O.B(hi); stage O'.A0
        RDB2(bb, 1, bB + 2048);
        if (more) STA2(1, 0, koO2);
        SBB; QUAD(acc, 1, 2, a1, bb); SBE;
        // P8: stage O'.A1; gate (forces E' complete)
        if (more) { STA2(1, 1, koO2); VMW(4); }
        SBB; QUAD(acc, 0, 2, a0, bb); SBE;
    }

    // epilogue: scatter fp32 rows to (B, E, CAP, D)
#pragma unroll
    for (int i = 0; i < 8; ++i) {
        const int mb = m0 + wm * 128 + i * 16 + quad * 4;
#pragma unroll
        for (int r = 0; r < 4; ++r) {
            const int m = mb + r;
            const int b = m >> 10, nc = m & 1023;
            float* orow = out + (size_t)((b * N_EXP + e) * CAPN + nc) * N_EMBD;
#pragma unroll
            for (int j = 0; j < 4; ++j)
                orow[n0 + wn * 64 + j * 16 + lo] = acc[i][j][r];
        }
    }
#undef STA2
#undef STB2
}

// ---------------------------------------------------------------------------
extern "C" void kernel_launch(void* const* d_in, const int* in_sizes, int n_in,
                              void* d_out, int out_size, void* d_ws, size_t ws_size,
                              hipStream_t stream) {
    const float* x     = (const float*)d_in[0];
    const float* cfc   = (const float*)d_in[1];
    const float* cproj = (const float*)d_in[2];
    const float* gamma = (const float*)d_in[3];
    const float* mbias = (const float*)d_in[4];
    float* out = (float*)d_out;

    unsigned short* h      = (unsigned short*)d_ws;
    unsigned short* cfcT   = h + 50331648ull;
    unsigned short* cprojT = cfcT + 25165824ull;
    unsigned short* gbuf   = cprojT + 12582912ull;
    const size_t need_batched = 444596224ull;   // bytes

    norm_convert_kernel<<<dim3(N_EXP * M_TOT / 4), dim3(256), 0, stream>>>(x, gamma, h);
    transpose_convert_kernel<<<dim3(2 * DIMH / 32, N_EMBD / 32, N_EXP), dim3(256), 0, stream>>>(
        cfc, cfcT, N_EMBD, 2 * DIMH);
    transpose_convert_kernel<<<dim3(N_EMBD / 32, DIMH / 32, N_EXP), dim3(256), 0, stream>>>(
        cproj, cprojT, DIMH, N_EMBD);

    if (ws_size >= need_batched) {
        gemm1_kernel<<<dim3(M_TOT / 256, DIMH / 128, N_EXP), dim3(512), 0, stream>>>(
            h, cfcT, mbias, gbuf, 0);
        gemm2_kernel<<<dim3(M_TOT / 256, N_EMBD / 256, N_EXP), dim3(512), 0, stream>>>(
            gbuf, cprojT, out, 0);
    } else {
        for (int e = 0; e < N_EXP; ++e) {
            gemm1_kernel<<<dim3(M_TOT / 256, DIMH / 128, 1), dim3(512), 0, stream>>>(
                h, cfcT, mbias, gbuf, e);
            gemm2_kernel<<<dim3(M_TOT / 256, N_EMBD / 256, 1), dim3(512), 0, stream>>>(
                gbuf, cprojT, out, e);
        }
    }
}